// Round 10
// baseline (43.619 us; speedup 1.0000x reference)
//
#include <hip/hip_runtime.h>

#define D   256
#define NB  128
#define NV  53
#define NR  8192            // rows per side (64*128)
#define V4  14              // v-groups of 4 (56 slots)
#define SLB (V4*NR*4)       // 458752 ushorts per slice
#define ESOFF (4*SLB)       // E (exp2) slices start here
#define A52   (13*NR*4)     // slice offset of v-slot 52
#define LOG2E 1.44269504088896340736f
#define LN2   0.69314718055994530942f

// ws (ushort units): raw slices PS@0 PI@SLB MS@2SLB MI@3SLB (bf16 of logit*log2e,
// bias folded into modern side); E slices = exp2(raw) at +ESOFF, same layout,
// E pad slots 53..55 zeroed.  slice element (v,row) at ((v>>2)*NR + row)*4 + (v&3)

typedef float  f4 __attribute__((ext_vector_type(4)));
typedef float  f2 __attribute__((ext_vector_type(2)));
typedef short  s8 __attribute__((ext_vector_type(8)));

__device__ __forceinline__ ushort f2bf(float f) {            // RNE f32 -> bf16
    uint u = __float_as_uint(f);
    u += 0x7fff + ((u >> 16) & 1);
    return (ushort)(u >> 16);
}
__device__ __forceinline__ float bflo(uint w) { return __uint_as_float(w << 16); }
__device__ __forceinline__ float bfhi(uint w) { return __uint_as_float(w & 0xffff0000u); }
__device__ __forceinline__ float fexp2(float x) { return __builtin_exp2f(x); }
__device__ __forceinline__ float flog2(float x) { return __builtin_log2f(x); }

// ---- p1: stage W coalesced -> swizzled LDS; 8-row tiles, 2 blocks/CU ----
// WL element (o,d) at byte o*512 + (2d ^ ((o&7)<<4)); o<53 sub, 53..105 ins
__global__ __launch_bounds__(256) void p1_kernel(
    const float* __restrict__ prior, const float* __restrict__ modern,
    const float* __restrict__ Wsub, const float* __restrict__ bsub,
    const float* __restrict__ Wins, const float* __restrict__ bins,
    ushort* __restrict__ wsb)
{
    __shared__ ushort WL[112 * 256];       // 57344 B
    const int tid = threadIdx.x;

    #pragma unroll
    for (int j = 0; j < 14; ++j) {         // 112 rows x 32 chunks, coalesced 32B/thread
        const int t  = j * 256 + tid;      // 0..3583
        const int o  = t >> 5, ch = t & 31;
        const float* w = nullptr;
        if (o < NV)       w = Wsub + o * D + ch * 8;
        else if (o < 106) w = Wins + (o - NV) * D + ch * 8;
        s8 q;
        if (w) {
            const f4 a = *(const f4*)w;
            const f4 b = *(const f4*)(w + 4);
            q[0]=(short)f2bf(a[0]*LOG2E); q[1]=(short)f2bf(a[1]*LOG2E);
            q[2]=(short)f2bf(a[2]*LOG2E); q[3]=(short)f2bf(a[3]*LOG2E);
            q[4]=(short)f2bf(b[0]*LOG2E); q[5]=(short)f2bf(b[1]*LOG2E);
            q[6]=(short)f2bf(b[2]*LOG2E); q[7]=(short)f2bf(b[3]*LOG2E);
        } else {
            #pragma unroll
            for (int i = 0; i < 8; ++i) q[i] = 0;
        }
        const int byteoff = o * 512 + ((ch * 16) ^ ((o & 7) << 4));
        *(s8*)((char*)WL + byteoff) = q;
    }
    __syncthreads();

    const int wave = tid >> 6, lane = tid & 63;
    const int lrow = lane & 15, lk = lane >> 4;
    const int tile8 = blockIdx.x * 4 + wave;          // 0..2047 (8-row tiles)
    const int side  = tile8 >> 10;                    // 0: prior, 1: modern
    const int row0  = (tile8 & 1023) << 3;
    const float* __restrict__ src =
        (side ? modern : prior) + (size_t)(row0 + (lrow & 7)) * D + lk * 8;

    f4 c[16];                              // hoist all ctx loads (ILP)
    #pragma unroll
    for (int s = 0; s < 8; ++s) {
        c[2*s]   = *(const f4*)(src + 32 * s);
        c[2*s+1] = *(const f4*)(src + 32 * s + 4);
    }

    f4 acc[7];
    #pragma unroll
    for (int nt = 0; nt < 7; ++nt) { acc[nt][0]=0.f; acc[nt][1]=0.f; acc[nt][2]=0.f; acc[nt][3]=0.f; }

    const int swzc = (lrow & 7) << 4;
    #pragma unroll
    for (int s = 0; s < 8; ++s) {
        s8 a;
        a[0]=(short)f2bf(c[2*s][0]);   a[1]=(short)f2bf(c[2*s][1]);
        a[2]=(short)f2bf(c[2*s][2]);   a[3]=(short)f2bf(c[2*s][3]);
        a[4]=(short)f2bf(c[2*s+1][0]); a[5]=(short)f2bf(c[2*s+1][1]);
        a[6]=(short)f2bf(c[2*s+1][2]); a[7]=(short)f2bf(c[2*s+1][3]);
        #pragma unroll
        for (int nt = 0; nt < 7; ++nt) {
            // B frag: W[v = nt*16+lrow][k = 32s+8lk+j]; swizzled, conflict-free
            const int byte = (nt * 16 + lrow) * 512 + ((s * 64 + lk * 16) ^ swzc);
            const s8 bfr = *(const s8*)((const char*)WL + byte);
            acc[nt] = __builtin_amdgcn_mfma_f32_16x16x32_bf16(a, bfr, acc[nt], 0, 0, 0);
        }
    }

    // epilogue: D rows 0..7 are the real rows (lk<2); raw + E stores
    if (lk < 2) {
        #pragma unroll
        for (int nt = 0; nt < 7; ++nt) {
            const int v = nt * 16 + lrow;
            if (v < 106) {
                const bool isS = v < NV;
                const int  vi  = isS ? v : v - NV;
                float bias = 0.f;
                if (side) bias = (isS ? bsub[v] : bins[v - NV]) * LOG2E;
                ushort* __restrict__ raw = wsb + (size_t)(side * 2 + (isS ? 0 : 1)) * SLB;
                ushort* __restrict__ Eb  = raw + ESOFF;
                const int a0 = (vi >> 2) * (NR * 4) + (vi & 3);
                #pragma unroll
                for (int r = 0; r < 4; ++r) {
                    const int row = row0 + 4 * lk + r;
                    const float val = acc[nt][r] + bias;
                    raw[a0 + row * 4] = f2bf(val);
                    Eb[a0 + row * 4]  = f2bf(fexp2(val));
                }
            }
        }
        if (lrow >= 10 && lrow <= 12) {              // E pads 53..55 <- 0
            const int vi = 43 + lrow;
            const int a0 = (vi >> 2) * (NR * 4) + (vi & 3);
            #pragma unroll
            for (int r = 0; r < 4; ++r) {
                const int row = row0 + 4 * lk + r;
                wsb[ESOFF + (size_t)(side * 2 + 0) * SLB + a0 + row * 4] = 0;
                wsb[ESOFF + (size_t)(side * 2 + 1) * SLB + a0 + row * 4] = 0;
            }
        }
    }
}

// ---- p2: S = dot(EP, EM) over 56 slots; lse = log2 S; XT=2, 4 waves/SIMD ----
__global__ __launch_bounds__(256) void p2_kernel(
    const ushort* __restrict__ wsb,
    const int* __restrict__ target, const int* __restrict__ srclen,
    const int* __restrict__ tgtlen, float* __restrict__ out)
{
    const int tid = threadIdx.x;
    const int b   = tid & 127;
    const int bid = blockIdx.x;
    const int xt  = bid & 31;                              // 0..31
    const int y   = ((bid >> 5) << 1) | (tid >> 7);        // 0..63
    const int yb  = y * NB + b;

    const int sl = srclen[b], tl = tgtlen[b];
    const bool ymask = y < tl;
    const bool hasT  = y < 63;
    const int  t     = hasT ? target[y * NB + b] : 0;
    const int  toff  = (t >> 2) * (NR * 4) + (t & 3);

    #pragma unroll 1
    for (int dist = 0; dist < 2; ++dist) {                 // 0: sub, 1: ins
        const ushort* __restrict__ Praw = wsb + dist * SLB;
        const ushort* __restrict__ Mraw = wsb + (2 + dist) * SLB;
        const ushort* __restrict__ PE   = Praw + ESOFF;
        const ushort* __restrict__ ME   = Mraw + ESOFF;

        f2 em0[V4], em1[V4];
        #pragma unroll
        for (int g = 0; g < V4; ++g) {
            const uint2 q = *(const uint2*)(ME + (g * NR + yb) * 4);
            em0[g][0] = bflo(q.x); em0[g][1] = bfhi(q.x);
            em1[g][0] = bflo(q.y); em1[g][1] = bfhi(q.y);
        }
        const float mlt = bflo((uint)Mraw[toff + yb * 4]);
        const float m52 = bflo((uint)Mraw[A52  + yb * 4]);

        float* __restrict__ o0 = out + dist * 524288;              // del / end
        float* __restrict__ o1 = out + 1048576 + dist * 516096;    // sub_probs / ins_probs

        #pragma unroll
        for (int xi = 0; xi < 2; ++xi) {
            const int x  = (xt << 1) + xi;
            const int xb = x * NB + b;
            const bool msk = (x < sl) & ymask;

            f2 s0; s0[0] = 0.f; s0[1] = 0.f;
            f2 s1; s1[0] = 0.f; s1[1] = 0.f;
            #pragma unroll
            for (int g = 0; g < V4; ++g) {
                const uint2 p = *(const uint2*)(PE + (g * NR + xb) * 4);
                f2 a; a[0] = bflo(p.x); a[1] = bfhi(p.x);
                f2 c; c[0] = bflo(p.y); c[1] = bfhi(p.y);
                s0 += a * em0[g];
                s1 += c * em1[g];
            }
            const float S  = (s0[0] + s0[1]) + (s1[0] + s1[1]);
            const float ls = flog2(S);

            const float l52 = bflo((uint)Praw[A52 + xb * 4]) + m52;
            o0[((x << 6) | y) * NB + b] = msk ? (l52 - ls) * LN2 : 0.f;
            if (hasT) {
                const float lt = bflo((uint)Praw[toff + xb * 4]) + mlt;
                o1[(x * 63 + y) * NB + b] = msk ? (lt - ls) * LN2 : 0.f;
            }
        }
    }
}

extern "C" void kernel_launch(void* const* d_in, const int* in_sizes, int n_in,
                              void* d_out, int out_size, void* d_ws, size_t ws_size,
                              hipStream_t stream) {
    const float* prior  = (const float*)d_in[0];
    const float* modern = (const float*)d_in[1];
    const float* Wsub   = (const float*)d_in[2];
    const float* bsub   = (const float*)d_in[3];
    const float* Wins   = (const float*)d_in[4];
    const float* bins   = (const float*)d_in[5];
    const int*   target = (const int*)d_in[6];
    const int*   srclen = (const int*)d_in[7];
    const int*   tgtlen = (const int*)d_in[8];
    ushort* wsb = (ushort*)d_ws;
    float*  out = (float*)d_out;

    // p1: 512 blocks x 4 waves x 8-row tiles = 2048 tiles; 2 blocks/CU (57 KB LDS)
    p1_kernel<<<512, 256, 0, stream>>>(prior, modern, Wsub, bsub, Wins, bins, wsb);
    // p2: XT=2, 1024 blocks -> 4 waves/SIMD
    p2_kernel<<<1024, 256, 0, stream>>>(wsb, target, srclen, tgtlen, out);
}

// Round 12
// 36.190 us; speedup vs baseline: 1.2053x; 1.2053x over previous
//
#include <hip/hip_runtime.h>

#define D   256
#define NB  128
#define NV  53
#define NR  8192            // rows per side (64*128)
#define V4  14              // v-groups of 4 (56 slots)
#define SLB (V4*NR*4)       // 458752 ushorts per slice
#define ESOFF (4*SLB)       // E (exp2) slices start here
#define A52   (13*NR*4)     // slice offset of v-slot 52
#define LOG2E 1.44269504088896340736f
#define LN2   0.69314718055994530942f

// ws (ushort units): raw slices PS@0 PI@SLB MS@2SLB MI@3SLB = bf16(logit*log2e,
// bias folded into modern side); E slices = bf16(exp2(raw)) at +ESOFF, same
// layout, pad slots 53..55 zeroed.
// slice element (v,row) at ((v>>2)*NR + row)*4 + (v&3)

typedef float  f4 __attribute__((ext_vector_type(4)));
typedef float  f2 __attribute__((ext_vector_type(2)));
typedef short  s8 __attribute__((ext_vector_type(8)));

__device__ __forceinline__ ushort f2bf(float f) {            // RNE f32 -> bf16
    uint u = __float_as_uint(f);
    u += 0x7fff + ((u >> 16) & 1);
    return (ushort)(u >> 16);
}
__device__ __forceinline__ float bflo(uint w) { return __uint_as_float(w << 16); }
__device__ __forceinline__ float bfhi(uint w) { return __uint_as_float(w & 0xffff0000u); }
__device__ __forceinline__ float fexp2(float x) { return __builtin_exp2f(x); }
__device__ __forceinline__ float flog2(float x) { return __builtin_log2f(x); }

// ---- p1: R4-p1 verbatim (in-block W rebuild, 7-nt MFMA) + E epilogue ----
// grid 256 x 256thr: 4 waves/block, 1 tile(16 rows)/wave, 1024 tiles total.
__global__ __launch_bounds__(256) void p1_kernel(
    const float* __restrict__ prior, const float* __restrict__ modern,
    const float* __restrict__ Wsub, const float* __restrict__ bsub,
    const float* __restrict__ Wins, const float* __restrict__ bins,
    ushort* __restrict__ wsb)
{
    // B fragments: WB[((nt*8+s)*64 + lane)*8 + j] = W^T[32s+8*(lane>>4)+j][nt*16+(lane&15)]
    __shared__ ushort WB[3584 * 8];        // 57344 B
    const int tid = threadIdx.x;

    #pragma unroll
    for (int i = 0; i < 14; ++i) {
        const int F  = tid + 256 * i;      // fragment-slot 0..3583
        const int l  = F & 63, s = (F >> 6) & 7, nt = F >> 9;
        const int o  = nt * 16 + (l & 15);
        const int d0 = 32 * s + 8 * (l >> 4);
        s8 bfr;
        if (o < NV) {
            const float* w = Wsub + o * D + d0;
            #pragma unroll
            for (int j = 0; j < 8; ++j) bfr[j] = (short)f2bf(w[j]);
        } else if (o < 106) {
            const float* w = Wins + (o - NV) * D + d0;
            #pragma unroll
            for (int j = 0; j < 8; ++j) bfr[j] = (short)f2bf(w[j]);
        } else {
            #pragma unroll
            for (int j = 0; j < 8; ++j) bfr[j] = 0;
        }
        *(s8*)&WB[F * 8] = bfr;
    }
    __syncthreads();

    const int wave = tid >> 6, lane = tid & 63;
    const int tile = blockIdx.x * 4 + wave;           // 0..1023
    const int side = tile >> 9;                       // 0: prior, 1: modern
    const int row0 = (tile & 511) << 4;
    const int lrow = lane & 15, lk = lane >> 4;
    const float* __restrict__ src =
        (side ? modern : prior) + (size_t)(row0 + lrow) * D + lk * 8;

    f4 c[16];                              // hoist all ctx loads (ILP)
    #pragma unroll
    for (int s = 0; s < 8; ++s) {
        c[2*s]   = *(const f4*)(src + 32 * s);
        c[2*s+1] = *(const f4*)(src + 32 * s + 4);
    }

    f4 acc[7];
    #pragma unroll
    for (int nt = 0; nt < 7; ++nt) { acc[nt][0]=0.f; acc[nt][1]=0.f; acc[nt][2]=0.f; acc[nt][3]=0.f; }

    #pragma unroll
    for (int s = 0; s < 8; ++s) {
        s8 a;
        a[0]=(short)f2bf(c[2*s][0]);   a[1]=(short)f2bf(c[2*s][1]);
        a[2]=(short)f2bf(c[2*s][2]);   a[3]=(short)f2bf(c[2*s][3]);
        a[4]=(short)f2bf(c[2*s+1][0]); a[5]=(short)f2bf(c[2*s+1][1]);
        a[6]=(short)f2bf(c[2*s+1][2]); a[7]=(short)f2bf(c[2*s+1][3]);
        #pragma unroll
        for (int nt = 0; nt < 7; ++nt) {
            const s8 bfr = *(const s8*)&WB[(((nt << 3) + s) * 64 + lane) * 8];
            acc[nt] = __builtin_amdgcn_mfma_f32_16x16x32_bf16(a, bfr, acc[nt], 0, 0, 0);
        }
    }

    // epilogue: scale to log2 space, store raw bf16 + E = exp2(raw) bf16
    // C/D: col(v) = nt*16 + lrow, row = row0 + 4*lk + reg   [m89]
    #pragma unroll
    for (int nt = 0; nt < 7; ++nt) {
        const int v = nt * 16 + lrow;
        if (v < 106) {
            const bool isS = v < NV;
            const int  vi  = isS ? v : v - NV;
            float bias = 0.f;
            if (side) bias = isS ? bsub[v] : bins[v - NV];
            ushort* __restrict__ raw = wsb + (size_t)(side * 2 + (isS ? 0 : 1)) * SLB;
            ushort* __restrict__ Eb  = raw + ESOFF;
            const int a0 = (vi >> 2) * (NR * 4) + (vi & 3);
            #pragma unroll
            for (int r = 0; r < 4; ++r) {
                const int row = row0 + 4 * lk + r;
                const float val = (acc[nt][r] + bias) * LOG2E;
                raw[a0 + row * 4] = f2bf(val);
                Eb[a0 + row * 4]  = f2bf(fexp2(val));
            }
        }
    }
    // E pad slots 53..55 <- 0 (lanes lrow 10..12 are the invalid v=106..108 lanes of nt=6)
    if (lrow >= 10 && lrow <= 12) {
        const int vi = 43 + lrow;                // 53..55
        const int a0 = (vi >> 2) * (NR * 4) + (vi & 3);
        #pragma unroll
        for (int r = 0; r < 4; ++r) {
            const int row = row0 + 4 * lk + r;
            wsb[ESOFF + (size_t)(side * 2 + 0) * SLB + a0 + row * 4] = 0;
            wsb[ESOFF + (size_t)(side * 2 + 1) * SLB + a0 + row * 4] = 0;
        }
    }
}

// ---- p2: S = dot(EP, EM) over 56 slots (pads 0); lse = log2 S; no exp/max in loop ----
__global__ __launch_bounds__(256) void p2_kernel(
    const ushort* __restrict__ wsb,
    const int* __restrict__ target, const int* __restrict__ srclen,
    const int* __restrict__ tgtlen, float* __restrict__ out)
{
    const int tid = threadIdx.x;
    const int b   = tid & 127;
    const int bid = blockIdx.x;
    const int xt  = ((bid & 7) << 1) | ((bid >> 3) & 1);   // 0..15 (XCD spread)
    const int y   = ((bid >> 4) << 1) | (tid >> 7);        // 0..63
    const int yb  = y * NB + b;

    const int sl = srclen[b], tl = tgtlen[b];
    const bool ymask = y < tl;
    const bool hasT  = y < 63;
    const int  t     = hasT ? target[y * NB + b] : 0;
    const int  toff  = (t >> 2) * (NR * 4) + (t & 3);

    #pragma unroll 1
    for (int dist = 0; dist < 2; ++dist) {                 // 0: sub, 1: ins
        const ushort* __restrict__ Praw = wsb + dist * SLB;
        const ushort* __restrict__ Mraw = wsb + (2 + dist) * SLB;
        const ushort* __restrict__ PE   = Praw + ESOFF;
        const ushort* __restrict__ ME   = Mraw + ESOFF;

        f2 em0[V4], em1[V4];
        #pragma unroll
        for (int g = 0; g < V4; ++g) {
            const uint2 q = *(const uint2*)(ME + (g * NR + yb) * 4);
            em0[g][0] = bflo(q.x); em0[g][1] = bfhi(q.x);
            em1[g][0] = bflo(q.y); em1[g][1] = bfhi(q.y);
        }
        const float mlt = bflo((uint)Mraw[toff + yb * 4]);
        const float m52 = bflo((uint)Mraw[A52  + yb * 4]);

        float* __restrict__ o0 = out + dist * 524288;              // del / end
        float* __restrict__ o1 = out + 1048576 + dist * 516096;    // sub_probs / ins_probs

        #pragma unroll
        for (int xi = 0; xi < 4; ++xi) {
            const int x  = (xt << 2) + xi;
            const int xb = x * NB + b;
            const bool msk = (x < sl) & ymask;

            f2 s0; s0[0] = 0.f; s0[1] = 0.f;
            f2 s1; s1[0] = 0.f; s1[1] = 0.f;
            #pragma unroll
            for (int g = 0; g < V4; ++g) {
                const uint2 p = *(const uint2*)(PE + (g * NR + xb) * 4);
                f2 a; a[0] = bflo(p.x); a[1] = bfhi(p.x);
                f2 c; c[0] = bflo(p.y); c[1] = bfhi(p.y);
                s0 += a * em0[g];
                s1 += c * em1[g];
            }
            const float S  = (s0[0] + s0[1]) + (s1[0] + s1[1]);
            const float ls = flog2(S);

            const float l52 = bflo((uint)Praw[A52 + xb * 4]) + m52;
            o0[((x << 6) | y) * NB + b] = msk ? (l52 - ls) * LN2 : 0.f;
            if (hasT) {
                const float lt = bflo((uint)Praw[toff + xb * 4]) + mlt;
                o1[(x * 63 + y) * NB + b] = msk ? (lt - ls) * LN2 : 0.f;
            }
        }
    }
}

extern "C" void kernel_launch(void* const* d_in, const int* in_sizes, int n_in,
                              void* d_out, int out_size, void* d_ws, size_t ws_size,
                              hipStream_t stream) {
    const float* prior  = (const float*)d_in[0];
    const float* modern = (const float*)d_in[1];
    const float* Wsub   = (const float*)d_in[2];
    const float* bsub   = (const float*)d_in[3];
    const float* Wins   = (const float*)d_in[4];
    const float* bins   = (const float*)d_in[5];
    const int*   target = (const int*)d_in[6];
    const int*   srclen = (const int*)d_in[7];
    const int*   tgtlen = (const int*)d_in[8];
    ushort* wsb = (ushort*)d_ws;
    float*  out = (float*)d_out;

    // p1: 256 blocks x 4 waves (R4 structure) + E epilogue
    p1_kernel<<<256, 256, 0, stream>>>(prior, modern, Wsub, bsub, Wins, bins, wsb);
    // p2: E-dot, XT=4, 512 blocks (R4 grid)
    p2_kernel<<<512, 256, 0, stream>>>(wsb, target, srclen, tgtlen, out);
}